// Round 2
// baseline (59.886 us; speedup 1.0000x reference)
//
#include <hip/hip_runtime.h>

#define B 16
#define ENC_T 512
#define ENC_DIM 512
#define DEC_T 2048

// Kernel 1: per-batch inclusive cumsum of durations (float ints) -> int32 cum[] in ws.
__global__ void cumsum_kernel(const float* __restrict__ enc_len, int* __restrict__ cum) {
    __shared__ float s[ENC_T];
    const int b = blockIdx.x;
    const int e = threadIdx.x;           // 512 threads
    float len = enc_len[(size_t)b * ENC_T + e];
    s[e] = len;
    __syncthreads();
    // Hillis-Steele inclusive scan over 512 elems
    for (int off = 1; off < ENC_T; off <<= 1) {
        float v = (e >= off) ? s[e - off] : 0.0f;
        __syncthreads();
        s[e] += v;
        __syncthreads();
    }
    cum[(size_t)b * ENC_T + e] = (int)s[e];   // durations are small ints; exact in f32
}

// Kernel 2: one block per (b,t) row. Binary search for segment, gather + one-hot write.
__global__ __launch_bounds__(128) void gather_kernel(const float* __restrict__ enc,
                                                     const int* __restrict__ cum,
                                                     float* __restrict__ out,
                                                     float* __restrict__ att) {
    const int bt = blockIdx.x;           // 0 .. B*DEC_T-1
    const int b  = bt >> 11;             // / DEC_T (2048)
    const int t  = bt & (DEC_T - 1);
    const int i  = threadIdx.x;          // 0..127

    const int* cb = cum + (size_t)b * ENC_T;
    // first e with cum[e] > t (upper_bound). Uniform across block -> broadcast loads,
    // uniform branch. Converges in <= 10 iters; mid <= 511 so no OOB.
    int lo = 0, hi = ENC_T;
    while (lo < hi) {
        int mid = (lo + hi) >> 1;
        if (cb[mid] > t) hi = mid; else lo = mid + 1;
    }
    const int seg = (lo < ENC_T) ? lo : -1;

    // out row: gather encoder row (or zeros), float4 per thread (128*4 = 512)
    float4 o = make_float4(0.f, 0.f, 0.f, 0.f);
    if (seg >= 0) {
        o = ((const float4*)(enc + ((size_t)b * ENC_T + seg) * ENC_DIM))[i];
    }
    ((float4*)(out + (size_t)bt * ENC_DIM))[i] = o;

    // att row: one-hot at seg
    float4 a = make_float4(0.f, 0.f, 0.f, 0.f);
    const int e0 = i * 4;
    if (seg >= e0 && seg < e0 + 4) {
        ((float*)&a)[seg - e0] = 1.0f;
    }
    ((float4*)(att + (size_t)bt * ENC_T))[i] = a;
}

extern "C" void kernel_launch(void* const* d_in, const int* in_sizes, int n_in,
                              void* d_out, int out_size, void* d_ws, size_t ws_size,
                              hipStream_t stream) {
    const float* enc     = (const float*)d_in[0];   // [B, ENC_T, ENC_DIM]
    const float* enc_len = (const float*)d_in[2];   // [B, ENC_T]
    int* cum = (int*)d_ws;                          // [B, ENC_T] int32 (32 KB)

    float* out = (float*)d_out;                          // [B, DEC_T, ENC_DIM]
    float* att = out + (size_t)B * DEC_T * ENC_DIM;      // [B, DEC_T, ENC_T]

    hipLaunchKernelGGL(cumsum_kernel, dim3(B), dim3(ENC_T), 0, stream, enc_len, cum);
    hipLaunchKernelGGL(gather_kernel, dim3(B * DEC_T), dim3(128), 0, stream,
                       enc, cum, out, att);
}

// Round 3
// 48.125 us; speedup vs baseline: 1.2444x; 1.2444x over previous
//
#include <hip/hip_runtime.h>

#define B 16
#define ENC_T 512
#define ENC_DIM 512
#define DEC_T 2048
#define ROWS 8   // rows per block in gather kernel

// Kernel 1: per-batch cumsum of durations + full segment-map expansion.
// segmap[b][t] = e such that start[e] <= t < end[e], or -1 if t >= total.
__global__ __launch_bounds__(512) void scan_segmap_kernel(const float* __restrict__ enc_len,
                                                          short* __restrict__ segmap) {
    __shared__ float sf[ENC_T];
    __shared__ int   si[ENC_T];
    const int b = blockIdx.x;
    const int e = threadIdx.x;           // 512 threads
    sf[e] = enc_len[(size_t)b * ENC_T + e];
    __syncthreads();
    // Hillis-Steele inclusive scan over 512 elems (proven correct in R2)
    for (int off = 1; off < ENC_T; off <<= 1) {
        float v = (e >= off) ? sf[e - off] : 0.0f;
        __syncthreads();
        sf[e] += v;
        __syncthreads();
    }
    si[e] = (int)sf[e];                  // durations are small ints; exact in f32
    __syncthreads();

    // each thread resolves 4 consecutive decoder steps t = 4e .. 4e+3
    short4 sv;
    #pragma unroll
    for (int q = 0; q < 4; ++q) {
        const int t = (e << 2) + q;
        int lo = 0, hi = ENC_T;
        while (lo < hi) {                // upper_bound: first e with cum[e] > t
            int mid = (lo + hi) >> 1;    // mid <= 511 inside loop -> no OOB
            if (si[mid] > t) hi = mid; else lo = mid + 1;
        }
        ((short*)&sv)[q] = (lo < ENC_T) ? (short)lo : (short)-1;
    }
    ((short4*)(segmap + (size_t)b * DEC_T))[e] = sv;   // coalesced 8B stores
}

// Kernel 2: pure streaming writer. 8 rows per block; threads 0-127 write the
// gathered out row (float4), threads 128-255 write the one-hot att row (float4).
__global__ __launch_bounds__(256) void gather_kernel(const float* __restrict__ enc,
                                                     const short* __restrict__ segmap,
                                                     float* __restrict__ out,
                                                     float* __restrict__ att) {
    const int bt0 = blockIdx.x * ROWS;   // ROWS divides DEC_T -> single b per block
    const int b   = bt0 >> 11;           // / DEC_T
    const int i   = threadIdx.x;

    // broadcast-load the 8 segment ids (independent, issued up front)
    int seg[ROWS];
    #pragma unroll
    for (int r = 0; r < ROWS; ++r) seg[r] = segmap[bt0 + r];

    if (i < 128) {
        // out rows: gather encoder row (or zeros), 128 x float4 = 512 floats
        #pragma unroll
        for (int r = 0; r < ROWS; ++r) {
            float4 o = make_float4(0.f, 0.f, 0.f, 0.f);
            const int s = seg[r];
            if (s >= 0)
                o = ((const float4*)(enc + ((size_t)b * ENC_T + s) * ENC_DIM))[i];
            ((float4*)(out + (size_t)(bt0 + r) * ENC_DIM))[i] = o;
        }
    } else {
        // att rows: one-hot at seg, no loads
        const int j  = i - 128;
        const int e0 = j << 2;
        #pragma unroll
        for (int r = 0; r < ROWS; ++r) {
            float4 a = make_float4(0.f, 0.f, 0.f, 0.f);
            const int s = seg[r];
            if (s >= e0 && s < e0 + 4) ((float*)&a)[s - e0] = 1.0f;
            ((float4*)(att + (size_t)(bt0 + r) * ENC_T))[j] = a;
        }
    }
}

extern "C" void kernel_launch(void* const* d_in, const int* in_sizes, int n_in,
                              void* d_out, int out_size, void* d_ws, size_t ws_size,
                              hipStream_t stream) {
    const float* enc     = (const float*)d_in[0];   // [B, ENC_T, ENC_DIM]
    const float* enc_len = (const float*)d_in[2];   // [B, ENC_T]
    short* segmap = (short*)d_ws;                   // [B, DEC_T] int16 (64 KB)

    float* out = (float*)d_out;                          // [B, DEC_T, ENC_DIM]
    float* att = out + (size_t)B * DEC_T * ENC_DIM;      // [B, DEC_T, ENC_T]

    hipLaunchKernelGGL(scan_segmap_kernel, dim3(B), dim3(ENC_T), 0, stream, enc_len, segmap);
    hipLaunchKernelGGL(gather_kernel, dim3(B * DEC_T / ROWS), dim3(256), 0, stream,
                       enc, segmap, out, att);
}

// Round 4
// 44.009 us; speedup vs baseline: 1.3607x; 1.0935x over previous
//
#include <hip/hip_runtime.h>

#define B 16
#define ENC_T 512
#define ENC_DIM 512
#define DEC_T 2048
#define ROWS 16                      // decoder rows per block
#define NBLK (B * DEC_T / ROWS)      // 2048 blocks

// One fused kernel: per-block wave-scan of durations + segment search + streaming writes.
__global__ __launch_bounds__(512) void fused_kernel(const float* __restrict__ enc,
                                                    const float* __restrict__ enc_len,
                                                    float* __restrict__ out,
                                                    float* __restrict__ att) {
    __shared__ int si[ENC_T];        // inclusive cumsum (= end[e])
    __shared__ int wsum[8];
    __shared__ int sseg[ROWS];

    const int tid = threadIdx.x;     // 0..511
    const int bt0 = blockIdx.x * ROWS;   // global row index of first row
    const int b   = bt0 >> 11;           // / DEC_T

    // ---- phase 1: cumsum of batch b durations (wave shfl scan, 8 waves) ----
    int v = (int)enc_len[(size_t)b * ENC_T + tid];   // small ints, exact
    const int lane = tid & 63;
    #pragma unroll
    for (int off = 1; off < 64; off <<= 1) {
        int u = __shfl_up(v, off, 64);
        if (lane >= off) v += u;
    }
    const int w = tid >> 6;
    if (lane == 63) wsum[w] = v;
    __syncthreads();
    int woff = 0;
    for (int k = 0; k < w; ++k) woff += wsum[k];     // <=7 broadcast LDS reads
    si[tid] = v + woff;
    __syncthreads();

    // ---- phase 2: segment id for each of this block's ROWS rows ----
    if (tid < ROWS) {
        const int t = (bt0 - (b << 11)) + tid;       // t within batch
        int lo = 0, hi = ENC_T;
        while (lo < hi) {                            // upper_bound: first si[e] > t
            int mid = (lo + hi) >> 1;
            if (si[mid] > t) hi = mid; else lo = mid + 1;
        }
        sseg[tid] = (lo < ENC_T) ? lo : -1;
    }
    __syncthreads();

    // ---- phase 3: stream the rows. groups 0,1 -> out; groups 2,3 -> att ----
    const int g = tid >> 7;          // 0..3 (two waves per group)
    const int j = tid & 127;
    if (g < 2) {
        #pragma unroll
        for (int r8 = 0; r8 < ROWS / 2; ++r8) {
            const int r = (r8 << 1) | g;
            const int s = sseg[r];
            float4 o = make_float4(0.f, 0.f, 0.f, 0.f);
            if (s >= 0)
                o = ((const float4*)(enc + ((size_t)b * ENC_T + s) * ENC_DIM))[j];
            ((float4*)(out + (size_t)(bt0 + r) * ENC_DIM))[j] = o;
        }
    } else {
        const int e0 = j << 2;
        #pragma unroll
        for (int r8 = 0; r8 < ROWS / 2; ++r8) {
            const int r = (r8 << 1) | (g - 2);
            const int s = sseg[r];
            float4 a = make_float4(0.f, 0.f, 0.f, 0.f);
            if (s >= e0 && s < e0 + 4) ((float*)&a)[s - e0] = 1.0f;
            ((float4*)(att + (size_t)(bt0 + r) * ENC_T))[j] = a;
        }
    }
}

extern "C" void kernel_launch(void* const* d_in, const int* in_sizes, int n_in,
                              void* d_out, int out_size, void* d_ws, size_t ws_size,
                              hipStream_t stream) {
    const float* enc     = (const float*)d_in[0];   // [B, ENC_T, ENC_DIM]
    const float* enc_len = (const float*)d_in[2];   // [B, ENC_T]

    float* out = (float*)d_out;                          // [B, DEC_T, ENC_DIM]
    float* att = out + (size_t)B * DEC_T * ENC_DIM;      // [B, DEC_T, ENC_T]

    hipLaunchKernelGGL(fused_kernel, dim3(NBLK), dim3(512), 0, stream,
                       enc, enc_len, out, att);
}